// Round 1
// baseline (424.550 us; speedup 1.0000x reference)
//
#include <hip/hip_runtime.h>
#include <hip/hip_bf16.h>
#include <stdint.h>

typedef float f32x4 __attribute__((ext_vector_type(4)));
typedef __attribute__((address_space(3))) uint32_t lds_u32_t;
typedef __attribute__((address_space(1))) const uint32_t glb_u32_t;

#define TOKENS 16384
#define DIM    4096
#define NEXP   64
#define TPB    32                 // tokens per block
#define KC     64                 // k-chunk
#define GSZ    (TOKENS*NEXP)      // gates elements
#define VSZ    (TOKENS*2)         // topk vals elements

// Block: 256 threads = (tr 0..15) x (ec 0..15).
// Thread computes 2 tokens (2*tr, 2*tr+1) x 4 experts (4*ec..4*ec+3).
// LDS tiles are 16B-slot XOR-swizzled (key = row pair/quad id) so that the
// strided ds_read_b128 in the inner loop spreads across bank quads; the
// swizzle is applied on the GLOBAL source address (global_load_lds writes
// linearly: wave-uniform base + lane*16).
__global__ __launch_bounds__(256, 2)
void router_kernel(const float* __restrict__ x,
                   const float* __restrict__ w,
                   float* __restrict__ out)
{
    __shared__ f32x4 xs4[TPB*KC/4];    // 512 slots  (8 KB)  [token][16]
    __shared__ f32x4 ws4[NEXP*KC/4];   // 1024 slots (16 KB) [expert][16]

    const int tid  = threadIdx.x;
    const int tr   = tid >> 4;    // 0..15
    const int ec   = tid & 15;    // 0..15
    const int tok0 = blockIdx.x * TPB;

    const f32x4 vzero = {0.f, 0.f, 0.f, 0.f};
    f32x4 acc[2][4];
#pragma unroll
    for (int i = 0; i < 2; ++i)
#pragma unroll
        for (int j = 0; j < 4; ++j) acc[i][j] = vzero;

    float* xsf = (float*)xs4;
    float* wsf = (float*)ws4;

    for (int k0 = 0; k0 < DIM; k0 += KC) {
        __syncthreads();   // previous chunk's compute done before overwrite
        // stage x tile: 8 KB, 2 x 16B per thread
#pragma unroll
        for (int n = 0; n < 2; ++n) {
            int idx   = tid + n*256;        // 0..511
            int row   = idx >> 4;           // local token 0..31
            int slot  = idx & 15;
            int kslot = slot ^ ((row >> 1) & 15);
            const float* gp = x + (size_t)(tok0 + row)*DIM + k0 + kslot*4;
            float* lp = xsf + idx*4;
            __builtin_amdgcn_global_load_lds((glb_u32_t*)gp, (lds_u32_t*)lp, 16, 0, 0);
        }
        // stage w tile: 16 KB, 4 x 16B per thread
#pragma unroll
        for (int n = 0; n < 4; ++n) {
            int idx   = tid + n*256;        // 0..1023
            int e     = idx >> 4;           // expert 0..63
            int slot  = idx & 15;
            int kslot = slot ^ ((e >> 2) & 15);
            const float* gp = w + (size_t)e*DIM + k0 + kslot*4;
            float* lp = wsf + idx*4;
            __builtin_amdgcn_global_load_lds((glb_u32_t*)gp, (lds_u32_t*)lp, 16, 0, 0);
        }
        __syncthreads();   // drains vmcnt before barrier

#pragma unroll
        for (int s = 0; s < 16; ++s) {
            const int sx = s ^ tr;          // undo x swizzle (key = row>>1 = tr)
            const int sw = s ^ ec;          // undo w swizzle (key = e>>2  = ec)
            f32x4 xv0 = xs4[(2*tr + 0)*16 + sx];
            f32x4 xv1 = xs4[(2*tr + 1)*16 + sx];
            f32x4 wv0 = ws4[(4*ec + 0)*16 + sw];
            f32x4 wv1 = ws4[(4*ec + 1)*16 + sw];
            f32x4 wv2 = ws4[(4*ec + 2)*16 + sw];
            f32x4 wv3 = ws4[(4*ec + 3)*16 + sw];
            acc[0][0] += xv0*wv0;  acc[0][1] += xv0*wv1;
            acc[0][2] += xv0*wv2;  acc[0][3] += xv0*wv3;
            acc[1][0] += xv1*wv0;  acc[1][1] += xv1*wv1;
            acc[1][2] += xv1*wv2;  acc[1][3] += xv1*wv3;
        }
    }

    // Epilogue: per-token softmax + top-2 across the 16-lane group (same tr).
#pragma unroll
    for (int i = 0; i < 2; ++i) {
        const int t = tok0 + 2*tr + i;
        float l[4];
#pragma unroll
        for (int j = 0; j < 4; ++j) {
            f32x4 a = acc[i][j];
            l[j] = (a[0] + a[1]) + (a[2] + a[3]);
        }
        // group max
        float m = fmaxf(fmaxf(l[0], l[1]), fmaxf(l[2], l[3]));
#pragma unroll
        for (int off = 1; off < 16; off <<= 1)
            m = fmaxf(m, __shfl_xor(m, off));
        // exp + group sum
        float e0 = expf(l[0]-m), e1 = expf(l[1]-m), e2 = expf(l[2]-m), e3 = expf(l[3]-m);
        float ssum = (e0+e1) + (e2+e3);
#pragma unroll
        for (int off = 1; off < 16; off <<= 1)
            ssum += __shfl_xor(ssum, off);
        float inv = 1.0f / ssum;
        f32x4 g = {e0*inv, e1*inv, e2*inv, e3*inv};
        *(f32x4*)(out + (size_t)t*NEXP + 4*ec) = g;

        // local top-2 (tie -> lower index, matching jax.lax.top_k)
        float v1 = l[0]; int i1 = 4*ec;
        float v2 = -__builtin_inff(); int i2 = 1 << 30;
#pragma unroll
        for (int j = 1; j < 4; ++j) {
            float lv = l[j]; int li = 4*ec + j;
            bool b1 = (lv > v1) || (lv == v1 && li < i1);
            bool b2 = (lv > v2) || (lv == v2 && li < i2);
            float pv1 = v1; int pi1 = i1;
            v1 = b1 ? lv : v1;   i1 = b1 ? li : i1;
            v2 = b1 ? pv1 : (b2 ? lv : v2);
            i2 = b1 ? pi1 : (b2 ? li : i2);
        }
        // 16-lane butterfly merge of (v1,i1,v2,i2)
#pragma unroll
        for (int off = 1; off < 16; off <<= 1) {
            float ov1 = __shfl_xor(v1, off); int oi1 = __shfl_xor(i1, off);
            float ov2 = __shfl_xor(v2, off); int oi2 = __shfl_xor(i2, off);
            bool afirst = (v1 > ov1) || (v1 == ov1 && i1 < oi1);
            float nv1, nv2; int ni1, ni2;
            if (afirst) {
                nv1 = v1; ni1 = i1;
                bool b = (v2 > ov1) || (v2 == ov1 && i2 < oi1);
                nv2 = b ? v2 : ov1;  ni2 = b ? i2 : oi1;
            } else {
                nv1 = ov1; ni1 = oi1;
                bool b = (ov2 > v1) || (ov2 == v1 && oi2 < i1);
                nv2 = b ? ov2 : v1;  ni2 = b ? oi2 : i1;
            }
            v1 = nv1; i1 = ni1; v2 = nv2; i2 = ni2;
        }
        if (ec == 0) {
            out[GSZ + 2*(size_t)t + 0] = expf(v1 - m) * inv;
            out[GSZ + 2*(size_t)t + 1] = expf(v2 - m) * inv;
            out[GSZ + VSZ + 2*(size_t)t + 0] = (float)i1;
            out[GSZ + VSZ + 2*(size_t)t + 1] = (float)i2;
        }
    }
}

extern "C" void kernel_launch(void* const* d_in, const int* in_sizes, int n_in,
                              void* d_out, int out_size, void* d_ws, size_t ws_size,
                              hipStream_t stream) {
    (void)in_sizes; (void)n_in; (void)d_ws; (void)ws_size; (void)out_size;
    const float* x = (const float*)d_in[0];
    const float* w = (const float*)d_in[1];
    float* out     = (float*)d_out;
    dim3 grid(TOKENS / TPB);   // 512 blocks
    dim3 block(256);
    router_kernel<<<grid, block, 0, stream>>>(x, w, out);
}

// Round 2
// 380.846 us; speedup vs baseline: 1.1148x; 1.1148x over previous
//
#include <hip/hip_runtime.h>
#include <stdint.h>

typedef float f32x4 __attribute__((ext_vector_type(4)));
typedef _Float16 f16;
typedef _Float16 f16x8 __attribute__((ext_vector_type(8)));

#define TOKENS 16384
#define DIM    4096
#define NEXP   64
#define BM     32              // tokens per block
#define KC     64              // k per chunk
#define NCHUNK (DIM/KC)
#define GSZ    (TOKENS*NEXP)
#define VSZ    (TOKENS*2)
#define BUFSZ  24576           // bytes per LDS buffer: XH 4K + XL 4K + WH 8K + WL 8K
#define LSTR   68              // epilogue logits row stride (floats)

// fp32 -> fp16 hi/lo split (Markidis): v = h + l + O(2^-22 |v|)
__device__ __forceinline__ void split8(f32x4 a, f32x4 b, f16x8& h, f16x8& l) {
#pragma unroll
    for (int i = 0; i < 4; ++i) {
        float v = a[i]; f16 hi = (f16)v;
        h[i] = hi; l[i] = (f16)(v - (float)hi);
    }
#pragma unroll
    for (int i = 0; i < 4; ++i) {
        float v = b[i]; f16 hi = (f16)v;
        h[4+i] = hi; l[4+i] = (f16)(v - (float)hi);
    }
}

// Block: 256 threads (4 waves). Per chunk: stage x[32][64]+w[64][64] f32 ->
// split fp16 -> LDS (16B slots XOR-swizzled by row&7), then MFMA
// 16x16x32_f16, 3-term split accumulate into f32 acc. Double-buffered LDS,
// ONE raw s_barrier per chunk (prefetch loads are register loads -> no
// vmcnt drain needed at the barrier; lgkmcnt(0) orders ds ops).
__global__ __launch_bounds__(256, 2)
void router_kernel(const float* __restrict__ x,
                   const float* __restrict__ w,
                   float* __restrict__ out)
{
    __shared__ unsigned char smem[2*BUFSZ];

    const int tid  = threadIdx.x;
    const int tok0 = blockIdx.x * BM;

    // staging decomposition: x: 8 f32/thread, w: 16 f32/thread
    const int xrow = tid >> 3, xks = tid & 7;     // x row 0..31, 8-f32 slot 0..7
    const int we   = tid >> 2, wq  = tid & 3;     // w row 0..63, 16-f32 quarter

    const float* xg = x + (size_t)(tok0 + xrow)*DIM + xks*8;
    const float* wg = w + (size_t)we*DIM + wq*16;

    // MFMA decomposition: wave wv -> M-tile (wv>>1), N-tile pair ((wv&1)*2)
    const int lane = tid & 63;
    const int wv   = tid >> 6;
    const int mt   = wv >> 1;
    const int ntb  = (wv & 1) * 2;
    const int frow = mt*16 + (lane & 15);   // token row in x tile
    const int fk   = lane >> 4;             // k-subgroup 0..3
    const int swz  = lane & 7;              // == frow&7 == expert&7

    f32x4 acc[2] = {{0,0,0,0},{0,0,0,0}};

    f32x4 xr0, xr1, wr0, wr1, wr2, wr3;
    xr0 = ((const f32x4*)xg)[0];  xr1 = ((const f32x4*)xg)[1];
    wr0 = ((const f32x4*)wg)[0];  wr1 = ((const f32x4*)wg)[1];
    wr2 = ((const f32x4*)wg)[2];  wr3 = ((const f32x4*)wg)[3];

    auto cw = [&](unsigned char* base) {
        f16* XH = (f16*)base;
        f16* XL = XH + BM*KC;
        f16* WH = XL + BM*KC;
        f16* WL = WH + NEXP*KC;
        f16x8 h, l;
        split8(xr0, xr1, h, l);
        int s = xks ^ (xrow & 7);
        *(f16x8*)(XH + xrow*KC + s*8) = h;
        *(f16x8*)(XL + xrow*KC + s*8) = l;
        split8(wr0, wr1, h, l);
        s = (wq*2) ^ (we & 7);
        *(f16x8*)(WH + we*KC + s*8) = h;
        *(f16x8*)(WL + we*KC + s*8) = l;
        split8(wr2, wr3, h, l);
        s = (wq*2 + 1) ^ (we & 7);
        *(f16x8*)(WH + we*KC + s*8) = h;
        *(f16x8*)(WL + we*KC + s*8) = l;
    };

    cw(smem);   // chunk 0 -> buf0

    for (int kc = 0; kc < NCHUNK; ++kc) {
        if (kc + 1 < NCHUNK) {     // prefetch next chunk into registers
            const float* xp = xg + (kc+1)*KC;
            const float* wp = wg + (kc+1)*KC;
            xr0 = ((const f32x4*)xp)[0];  xr1 = ((const f32x4*)xp)[1];
            wr0 = ((const f32x4*)wp)[0];  wr1 = ((const f32x4*)wp)[1];
            wr2 = ((const f32x4*)wp)[2];  wr3 = ((const f32x4*)wp)[3];
        }
        // drain ds_writes (and prior ds_reads), then sync; vmcnt NOT drained
        asm volatile("s_waitcnt lgkmcnt(0)" ::: "memory");
        __builtin_amdgcn_s_barrier();

        const unsigned char* base = smem + (size_t)(kc & 1)*BUFSZ;
        const f16* XH = (const f16*)base;
        const f16* XL = XH + BM*KC;
        const f16* WH = XL + BM*KC;
        const f16* WL = WH + NEXP*KC;
#pragma unroll
        for (int ks = 0; ks < 2; ++ks) {
            const int sl = (ks*4 + fk) ^ swz;
            f16x8 ah = *(const f16x8*)(XH + frow*KC + sl*8);
            f16x8 al = *(const f16x8*)(XL + frow*KC + sl*8);
#pragma unroll
            for (int n = 0; n < 2; ++n) {
                const int e = (ntb + n)*16 + (lane & 15);
                f16x8 bh = *(const f16x8*)(WH + e*KC + sl*8);
                f16x8 bl = *(const f16x8*)(WL + e*KC + sl*8);
                acc[n] = __builtin_amdgcn_mfma_f32_16x16x32_f16(ah, bh, acc[n], 0, 0, 0);
                acc[n] = __builtin_amdgcn_mfma_f32_16x16x32_f16(ah, bl, acc[n], 0, 0, 0);
                acc[n] = __builtin_amdgcn_mfma_f32_16x16x32_f16(al, bh, acc[n], 0, 0, 0);
            }
        }
        if (kc + 1 < NCHUNK) cw(smem + (size_t)((kc+1) & 1)*BUFSZ);
    }

    // ---- epilogue: logits -> LDS (buf0 area; last compute used buf1) ----
    float* lg = (float*)smem;
#pragma unroll
    for (int n = 0; n < 2; ++n) {
        const int e = (ntb + n)*16 + (lane & 15);
#pragma unroll
        for (int i = 0; i < 4; ++i) {
            const int trow = mt*16 + fk*4 + i;   // C/D: col=lane&15, row=fk*4+reg
            lg[trow*LSTR + e] = acc[n][i];
        }
    }
    __syncthreads();

    // softmax + top-2: 8 lanes per token
    const int st = tid >> 3;      // token 0..31
    const int sg = tid & 7;       // expert octet
    const float* rowp = lg + st*LSTR + sg*8;
    float g[8];
#pragma unroll
    for (int j = 0; j < 8; ++j) g[j] = rowp[j];
    float m = g[0];
#pragma unroll
    for (int j = 1; j < 8; ++j) m = fmaxf(m, g[j]);
#pragma unroll
    for (int off = 1; off < 8; off <<= 1) m = fmaxf(m, __shfl_xor(m, off));
    float s = 0.f;
#pragma unroll
    for (int j = 0; j < 8; ++j) { g[j] = expf(g[j] - m); s += g[j]; }
#pragma unroll
    for (int off = 1; off < 8; off <<= 1) s += __shfl_xor(s, off);
    const float inv = 1.0f / s;
#pragma unroll
    for (int j = 0; j < 8; ++j) g[j] *= inv;

    const size_t t = (size_t)tok0 + st;
    f32x4 g0 = {g[0],g[1],g[2],g[3]}, g1 = {g[4],g[5],g[6],g[7]};
    *(f32x4*)(out + t*NEXP + sg*8)     = g0;
    *(f32x4*)(out + t*NEXP + sg*8 + 4) = g1;

    // top-2 on gate values (monotone w/ logits; matches ref top_k(gates)),
    // tie -> lower index
    float v1 = g[0]; int i1 = sg*8;
    float v2 = -__builtin_inff(); int i2 = 1 << 30;
#pragma unroll
    for (int j = 1; j < 8; ++j) {
        float lv = g[j]; int li = sg*8 + j;
        bool b1 = (lv > v1) || (lv == v1 && li < i1);
        bool b2 = (lv > v2) || (lv == v2 && li < i2);
        float pv1 = v1; int pi1 = i1;
        v1 = b1 ? lv : v1;  i1 = b1 ? li : i1;
        v2 = b1 ? pv1 : (b2 ? lv : v2);
        i2 = b1 ? pi1 : (b2 ? li : i2);
    }
#pragma unroll
    for (int off = 1; off < 8; off <<= 1) {
        float ov1 = __shfl_xor(v1, off); int oi1 = __shfl_xor(i1, off);
        float ov2 = __shfl_xor(v2, off); int oi2 = __shfl_xor(i2, off);
        bool afirst = (v1 > ov1) || (v1 == ov1 && i1 < oi1);
        float nv1, nv2; int ni1, ni2;
        if (afirst) {
            nv1 = v1; ni1 = i1;
            bool b = (v2 > ov1) || (v2 == ov1 && i2 < oi1);
            nv2 = b ? v2 : ov1; ni2 = b ? i2 : oi1;
        } else {
            nv1 = ov1; ni1 = oi1;
            bool b = (ov2 > v1) || (ov2 == v1 && oi2 < i1);
            nv2 = b ? ov2 : v1; ni2 = b ? oi2 : i1;
        }
        v1 = nv1; i1 = ni1; v2 = nv2; i2 = ni2;
    }
    if (sg == 0) {
        out[GSZ + 2*t]           = v1;
        out[GSZ + 2*t + 1]       = v2;
        out[GSZ + VSZ + 2*t]     = (float)i1;
        out[GSZ + VSZ + 2*t + 1] = (float)i2;
    }
}

extern "C" void kernel_launch(void* const* d_in, const int* in_sizes, int n_in,
                              void* d_out, int out_size, void* d_ws, size_t ws_size,
                              hipStream_t stream) {
    (void)in_sizes; (void)n_in; (void)d_ws; (void)ws_size; (void)out_size;
    const float* x = (const float*)d_in[0];
    const float* w = (const float*)d_in[1];
    float* out     = (float*)d_out;
    dim3 grid(TOKENS / BM);   // 512 blocks
    dim3 block(256);
    router_kernel<<<grid, block, 0, stream>>>(x, w, out);
}

// Round 4
// 374.495 us; speedup vs baseline: 1.1337x; 1.0170x over previous
//
#include <hip/hip_runtime.h>
#include <stdint.h>

typedef float f32x4 __attribute__((ext_vector_type(4)));
typedef _Float16 f16;
typedef _Float16 f16x8 __attribute__((ext_vector_type(8)));

#define TOKENS 16384
#define DIM    4096
#define NEXP   64
#define BM     32                  // tokens per block
#define GSZ    (TOKENS*NEXP)
#define VSZ    (TOKENS*2)
#define WFRAG  262144              // f16 elems per split array: 128 kk * 4 nt * 64 lanes * 8

// fp32 -> fp16 hi/lo split (Markidis): v = h + l + O(2^-22 |v|)
__device__ __forceinline__ void split8(f32x4 a, f32x4 b, f16x8& h, f16x8& l) {
#pragma unroll
    for (int i = 0; i < 4; ++i) {
        float v = a[i]; f16 hi = (f16)v;
        h[i] = hi; l[i] = (f16)(v - (float)hi);
    }
#pragma unroll
    for (int i = 0; i < 4; ++i) {
        float v = b[i]; f16 hi = (f16)v;
        h[4+i] = hi; l[4+i] = (f16)(v - (float)hi);
    }
}

// Kernel A: split w into fp16 hi/lo, stored in MFMA B-fragment order:
// slot s = (kk*4 + nt)*64 + lane  ->  expert e = nt*16 + (lane&15),
// k = kk*32 + (lane>>4)*8, 8 contiguous f16.  1 MB total, runs once per call.
__global__ void split_w_kernel(const float* __restrict__ w,
                               f16* __restrict__ WH, f16* __restrict__ WL) {
    const int s    = blockIdx.x * 256 + threadIdx.x;    // 0..32767
    const int lane = s & 63;
    const int nt   = (s >> 6) & 3;
    const int kk   = s >> 8;
    const int e    = nt*16 + (lane & 15);
    const int k8   = kk*32 + (lane >> 4)*8;
    const f32x4* wp = (const f32x4*)(w + (size_t)e*DIM + k8);
    f32x4 a = wp[0], b = wp[1];
    f16x8 h, l;
    split8(a, b, h, l);
    *(f16x8*)(WH + (size_t)s*8) = h;
    *(f16x8*)(WL + (size_t)s*8) = l;
}

// Kernel B: 512 threads = 8 waves. Wave wv owns K-slice [wv*512, wv*512+512)
// and computes the full 32-token x 64-expert tile for that slice: per 32-k
// step, 2 A-fragments loaded from global + split in-register, 8 pre-split
// B-fragments loaded coalesced, 24 MFMA (3-term fp32-emulation). No LDS, no
// barriers in the main loop. Epilogue: LDS reduce of 8 partials + softmax/top2.
__global__ __launch_bounds__(512, 4)
void router_kernel(const float* __restrict__ x,
                   const f16* __restrict__ WH, const f16* __restrict__ WL,
                   float* __restrict__ out)
{
    __shared__ float red[4][BM*NEXP];   // 32 KB

    const int tid  = threadIdx.x;
    const int lane = tid & 63;
    const int wv   = tid >> 6;          // 0..7
    const int tok0 = blockIdx.x * BM;
    const int l15  = lane & 15;
    const int lk   = lane >> 4;         // 0..3

    const float* ax = x + (size_t)(tok0 + l15)*DIM + wv*512 + lk*8;
    const f16x8* BH = (const f16x8*)WH;
    const f16x8* BL = (const f16x8*)WL;
    const int kk0 = wv * 16;            // 32-k step base

    f32x4 acc[2][4];
#pragma unroll
    for (int m = 0; m < 2; ++m)
#pragma unroll
        for (int n = 0; n < 4; ++n) acc[m][n] = (f32x4){0.f,0.f,0.f,0.f};

#pragma unroll
    for (int s = 0; s < 16; ++s) {
        const float* ap = ax + s*32;
        f32x4 a00 = *(const f32x4*)(ap);
        f32x4 a01 = *(const f32x4*)(ap + 4);
        f32x4 a10 = *(const f32x4*)(ap + (size_t)16*DIM);
        f32x4 a11 = *(const f32x4*)(ap + (size_t)16*DIM + 4);
        f16x8 bh[4], bl[4];
#pragma unroll
        for (int n = 0; n < 4; ++n) {
            const int idx = ((kk0 + s)*4 + n)*64 + lane;
            bh[n] = BH[idx];
            bl[n] = BL[idx];
        }
        f16x8 ah0, al0, ah1, al1;
        split8(a00, a01, ah0, al0);
        split8(a10, a11, ah1, al1);
#pragma unroll
        for (int n = 0; n < 4; ++n) {
            acc[0][n] = __builtin_amdgcn_mfma_f32_16x16x32_f16(ah0, bh[n], acc[0][n], 0, 0, 0);
            acc[0][n] = __builtin_amdgcn_mfma_f32_16x16x32_f16(ah0, bl[n], acc[0][n], 0, 0, 0);
            acc[0][n] = __builtin_amdgcn_mfma_f32_16x16x32_f16(al0, bh[n], acc[0][n], 0, 0, 0);
            acc[1][n] = __builtin_amdgcn_mfma_f32_16x16x32_f16(ah1, bh[n], acc[1][n], 0, 0, 0);
            acc[1][n] = __builtin_amdgcn_mfma_f32_16x16x32_f16(ah1, bl[n], acc[1][n], 0, 0, 0);
            acc[1][n] = __builtin_amdgcn_mfma_f32_16x16x32_f16(al1, bh[n], acc[1][n], 0, 0, 0);
        }
    }

    // ---- cross-wave reduction: two passes into red[0..3] ----
    // C/D fragment: col = lane&15 (expert within nt), row = lk*4 + i (token within mt)
    if (wv < 4) {
#pragma unroll
        for (int m = 0; m < 2; ++m)
#pragma unroll
            for (int n = 0; n < 4; ++n)
#pragma unroll
                for (int i = 0; i < 4; ++i)
                    red[wv][(m*16 + lk*4 + i)*NEXP + n*16 + l15] = acc[m][n][i];
    }
    __syncthreads();
    if (wv >= 4) {
#pragma unroll
        for (int m = 0; m < 2; ++m)
#pragma unroll
            for (int n = 0; n < 4; ++n)
#pragma unroll
                for (int i = 0; i < 4; ++i)
                    red[wv-4][(m*16 + lk*4 + i)*NEXP + n*16 + l15] += acc[m][n][i];
    }
    __syncthreads();

    // ---- softmax + top-2: 16 lanes per token, 4 experts per lane ----
    const int st = tid >> 4;       // token 0..31
    const int sg = tid & 15;       // expert quad 0..15
    const int ei = st*NEXP + sg*4;
    f32x4 s0 = *(const f32x4*)(&red[0][ei]);
    f32x4 s1 = *(const f32x4*)(&red[1][ei]);
    f32x4 s2 = *(const f32x4*)(&red[2][ei]);
    f32x4 s3 = *(const f32x4*)(&red[3][ei]);
    f32x4 lt = (s0 + s1) + (s2 + s3);
    float l[4] = {lt[0], lt[1], lt[2], lt[3]};

    float m = fmaxf(fmaxf(l[0], l[1]), fmaxf(l[2], l[3]));
#pragma unroll
    for (int off = 1; off < 16; off <<= 1) m = fmaxf(m, __shfl_xor(m, off));
    float g[4];
    float ssum = 0.f;
#pragma unroll
    for (int j = 0; j < 4; ++j) { g[j] = expf(l[j] - m); ssum += g[j]; }
#pragma unroll
    for (int off = 1; off < 16; off <<= 1) ssum += __shfl_xor(ssum, off);
    const float inv = 1.0f / ssum;
#pragma unroll
    for (int j = 0; j < 4; ++j) g[j] *= inv;

    const size_t t = (size_t)tok0 + st;
    f32x4 gv = {g[0], g[1], g[2], g[3]};
    *(f32x4*)(out + t*NEXP + sg*4) = gv;

    // top-2 on gate values (tie -> lower index, matching jax.lax.top_k)
    float v1 = g[0]; int i1 = sg*4;
    float v2 = -__builtin_inff(); int i2 = 1 << 30;
#pragma unroll
    for (int j = 1; j < 4; ++j) {
        float lv = g[j]; int li = sg*4 + j;
        bool b1 = (lv > v1) || (lv == v1 && li < i1);
        bool b2 = (lv > v2) || (lv == v2 && li < i2);
        float pv1 = v1; int pi1 = i1;
        v1 = b1 ? lv : v1;  i1 = b1 ? li : i1;
        v2 = b1 ? pv1 : (b2 ? lv : v2);
        i2 = b1 ? pi1 : (b2 ? li : i2);
    }
#pragma unroll
    for (int off = 1; off < 16; off <<= 1) {
        float ov1 = __shfl_xor(v1, off); int oi1 = __shfl_xor(i1, off);
        float ov2 = __shfl_xor(v2, off); int oi2 = __shfl_xor(i2, off);
        bool afirst = (v1 > ov1) || (v1 == ov1 && i1 < oi1);
        float nv1, nv2; int ni1, ni2;
        if (afirst) {
            nv1 = v1; ni1 = i1;
            bool b = (v2 > ov1) || (v2 == ov1 && i2 < oi1);
            nv2 = b ? v2 : ov1; ni2 = b ? i2 : oi1;
        } else {
            nv1 = ov1; ni1 = oi1;
            bool b = (ov2 > v1) || (ov2 == v1 && oi2 < i1);
            nv2 = b ? ov2 : v1; ni2 = b ? oi2 : i1;
        }
        v1 = nv1; i1 = ni1; v2 = nv2; i2 = ni2;
    }
    if (sg == 0) {
        out[GSZ + 2*t]           = v1;
        out[GSZ + 2*t + 1]       = v2;
        out[GSZ + VSZ + 2*t]     = (float)i1;
        out[GSZ + VSZ + 2*t + 1] = (float)i2;
    }
}

extern "C" void kernel_launch(void* const* d_in, const int* in_sizes, int n_in,
                              void* d_out, int out_size, void* d_ws, size_t ws_size,
                              hipStream_t stream) {
    (void)in_sizes; (void)n_in; (void)ws_size; (void)out_size;
    const float* x = (const float*)d_in[0];
    const float* w = (const float*)d_in[1];
    float* out     = (float*)d_out;
    f16* WH = (f16*)d_ws;
    f16* WL = WH + WFRAG;

    split_w_kernel<<<128, 256, 0, stream>>>(w, WH, WL);
    router_kernel<<<TOKENS/BM, 512, 0, stream>>>(x, WH, WL, out);
}

// Round 5
// 371.581 us; speedup vs baseline: 1.1426x; 1.0078x over previous
//
#include <hip/hip_runtime.h>
#include <stdint.h>

typedef float f32x4 __attribute__((ext_vector_type(4)));
typedef _Float16 f16;
typedef _Float16 f16x8 __attribute__((ext_vector_type(8)));

#define TOKENS 16384
#define DIM    4096
#define NEXP   64
#define BM     32                  // tokens per block
#define GSZ    (TOKENS*NEXP)
#define VSZ    (TOKENS*2)
#define WFRAG  262144              // f16 elems per split array: 128 kk * 4 nt * 64 lanes * 8
#define STEPS  16                  // 32-k steps per wave (wave K-slice = 512)

// fp32 -> fp16 hi/lo split (Markidis): v = h + l + O(2^-22 |v|)
__device__ __forceinline__ void split8(f32x4 a, f32x4 b, f16x8& h, f16x8& l) {
#pragma unroll
    for (int i = 0; i < 4; ++i) {
        float v = a[i]; f16 hi = (f16)v;
        h[i] = hi; l[i] = (f16)(v - (float)hi);
    }
#pragma unroll
    for (int i = 0; i < 4; ++i) {
        float v = b[i]; f16 hi = (f16)v;
        h[4+i] = hi; l[4+i] = (f16)(v - (float)hi);
    }
}

// Kernel A: split w into fp16 hi/lo in MFMA B-fragment order:
// slot s = (kk*4 + nt)*64 + lane -> expert e = nt*16 + (lane&15),
// k = kk*32 + (lane>>4)*8, 8 contiguous f16. 1 MB total.
__global__ void split_w_kernel(const float* __restrict__ w,
                               f16* __restrict__ WH, f16* __restrict__ WL) {
    const int s    = blockIdx.x * 256 + threadIdx.x;    // 0..32767
    const int lane = s & 63;
    const int nt   = (s >> 6) & 3;
    const int kk   = s >> 8;
    const int e    = nt*16 + (lane & 15);
    const int k8   = kk*32 + (lane >> 4)*8;
    const f32x4* wp = (const f32x4*)(w + (size_t)e*DIM + k8);
    f32x4 a = wp[0], b = wp[1];
    f16x8 h, l;
    split8(a, b, h, l);
    *(f16x8*)(WH + (size_t)s*8) = h;
    *(f16x8*)(WL + (size_t)s*8) = l;
}

// Kernel B: 512 threads = 8 K-split waves, BM=32 tokens x 64 experts/block.
// Non-unrolled step loop; x double-buffered in named registers (prefetch
// issued FIRST each step), B fragments 1-deep rotating prefetch. No LDS /
// barriers in main loop. ~114 live VGPRs -> no spill at the 128 cap.
__global__ __launch_bounds__(512, 4)
void router_kernel(const float* __restrict__ x,
                   const f16* __restrict__ WH, const f16* __restrict__ WL,
                   float* __restrict__ out)
{
    __shared__ float red[4][BM*NEXP];   // 32 KB

    const int tid  = threadIdx.x;
    const int lane = tid & 63;
    const int wv   = tid >> 6;          // 0..7
    const int tok0 = blockIdx.x * BM;
    const int l15  = lane & 15;
    const int lk   = lane >> 4;         // 0..3

    const float* ax = x + (size_t)(tok0 + l15)*DIM + wv*512 + lk*8;
    const f16x8* BH = (const f16x8*)WH;
    const f16x8* BL = (const f16x8*)WL;
    const int fb0 = (wv*16)*4*64 + lane;   // B frag index base for step 0

    f32x4 acc[2][4];
#pragma unroll
    for (int m = 0; m < 2; ++m)
#pragma unroll
        for (int n = 0; n < 4; ++n) acc[m][n] = (f32x4){0.f,0.f,0.f,0.f};

    // preload step 0 x
    f32x4 c00 = *(const f32x4*)(ax);
    f32x4 c01 = *(const f32x4*)(ax + 4);
    f32x4 c10 = *(const f32x4*)(ax + (size_t)16*DIM);
    f32x4 c11 = *(const f32x4*)(ax + (size_t)16*DIM + 4);

    for (int s = 0; s < STEPS; ++s) {
        // 1) issue next-step x loads first (longest latency path: L3/HBM)
        f32x4 n00, n01, n10, n11;
        if (s + 1 < STEPS) {
            const float* np = ax + (s+1)*32;
            n00 = *(const f32x4*)(np);
            n01 = *(const f32x4*)(np + 4);
            n10 = *(const f32x4*)(np + (size_t)16*DIM);
            n11 = *(const f32x4*)(np + (size_t)16*DIM + 4);
        }
        // 2) first B fragment pair for this step
        const int ib = fb0 + s*4*64;
        f16x8 bh0 = BH[ib], bl0 = BL[ib];
        // 3) split current x in-register
        f16x8 ah0, al0, ah1, al1;
        split8(c00, c01, ah0, al0);
        split8(c10, c11, ah1, al1);
        // 4) n-loop with 1-deep B prefetch
#pragma unroll
        for (int n = 0; n < 4; ++n) {
            f16x8 bhn, bln;
            if (n < 3) { bhn = BH[ib + (n+1)*64]; bln = BL[ib + (n+1)*64]; }
            acc[0][n] = __builtin_amdgcn_mfma_f32_16x16x32_f16(ah0, bh0, acc[0][n], 0, 0, 0);
            acc[0][n] = __builtin_amdgcn_mfma_f32_16x16x32_f16(ah0, bl0, acc[0][n], 0, 0, 0);
            acc[0][n] = __builtin_amdgcn_mfma_f32_16x16x32_f16(al0, bh0, acc[0][n], 0, 0, 0);
            acc[1][n] = __builtin_amdgcn_mfma_f32_16x16x32_f16(ah1, bh0, acc[1][n], 0, 0, 0);
            acc[1][n] = __builtin_amdgcn_mfma_f32_16x16x32_f16(ah1, bl0, acc[1][n], 0, 0, 0);
            acc[1][n] = __builtin_amdgcn_mfma_f32_16x16x32_f16(al1, bh0, acc[1][n], 0, 0, 0);
            bh0 = bhn; bl0 = bln;
        }
        // 5) rotate x buffers
        c00 = n00; c01 = n01; c10 = n10; c11 = n11;
    }

    // ---- cross-wave reduction: two passes into red[0..3] ----
    // C/D fragment: col = lane&15 (expert within nt), row = lk*4 + i
    if (wv < 4) {
#pragma unroll
        for (int m = 0; m < 2; ++m)
#pragma unroll
            for (int n = 0; n < 4; ++n)
#pragma unroll
                for (int i = 0; i < 4; ++i)
                    red[wv][(m*16 + lk*4 + i)*NEXP + n*16 + l15] = acc[m][n][i];
    }
    __syncthreads();
    if (wv >= 4) {
#pragma unroll
        for (int m = 0; m < 2; ++m)
#pragma unroll
            for (int n = 0; n < 4; ++n)
#pragma unroll
                for (int i = 0; i < 4; ++i)
                    red[wv-4][(m*16 + lk*4 + i)*NEXP + n*16 + l15] += acc[m][n][i];
    }
    __syncthreads();

    // ---- softmax + top-2: 16 lanes per token, 4 experts per lane ----
    const int st = tid >> 4;       // token 0..31
    const int sg = tid & 15;       // expert quad 0..15
    const int ei = st*NEXP + sg*4;
    f32x4 s0 = *(const f32x4*)(&red[0][ei]);
    f32x4 s1 = *(const f32x4*)(&red[1][ei]);
    f32x4 s2 = *(const f32x4*)(&red[2][ei]);
    f32x4 s3 = *(const f32x4*)(&red[3][ei]);
    f32x4 lt = (s0 + s1) + (s2 + s3);
    float l[4] = {lt[0], lt[1], lt[2], lt[3]};

    float m = fmaxf(fmaxf(l[0], l[1]), fmaxf(l[2], l[3]));
#pragma unroll
    for (int off = 1; off < 16; off <<= 1) m = fmaxf(m, __shfl_xor(m, off));
    float g[4];
    float ssum = 0.f;
#pragma unroll
    for (int j = 0; j < 4; ++j) { g[j] = expf(l[j] - m); ssum += g[j]; }
#pragma unroll
    for (int off = 1; off < 16; off <<= 1) ssum += __shfl_xor(ssum, off);
    const float inv = 1.0f / ssum;
#pragma unroll
    for (int j = 0; j < 4; ++j) g[j] *= inv;

    const size_t t = (size_t)tok0 + st;
    f32x4 gv = {g[0], g[1], g[2], g[3]};
    *(f32x4*)(out + t*NEXP + sg*4) = gv;

    // top-2 on gate values (tie -> lower index, matching jax.lax.top_k)
    float v1 = g[0]; int i1 = sg*4;
    float v2 = -__builtin_inff(); int i2 = 1 << 30;
#pragma unroll
    for (int j = 1; j < 4; ++j) {
        float lv = g[j]; int li = sg*4 + j;
        bool b1 = (lv > v1) || (lv == v1 && li < i1);
        bool b2 = (lv > v2) || (lv == v2 && li < i2);
        float pv1 = v1; int pi1 = i1;
        v1 = b1 ? lv : v1;  i1 = b1 ? li : i1;
        v2 = b1 ? pv1 : (b2 ? lv : v2);
        i2 = b1 ? pi1 : (b2 ? li : i2);
    }
#pragma unroll
    for (int off = 1; off < 16; off <<= 1) {
        float ov1 = __shfl_xor(v1, off); int oi1 = __shfl_xor(i1, off);
        float ov2 = __shfl_xor(v2, off); int oi2 = __shfl_xor(i2, off);
        bool afirst = (v1 > ov1) || (v1 == ov1 && i1 < oi1);
        float nv1, nv2; int ni1, ni2;
        if (afirst) {
            nv1 = v1; ni1 = i1;
            bool b = (v2 > ov1) || (v2 == ov1 && i2 < oi1);
            nv2 = b ? v2 : ov1; ni2 = b ? i2 : oi1;
        } else {
            nv1 = ov1; ni1 = oi1;
            bool b = (ov2 > v1) || (ov2 == v1 && oi2 < i1);
            nv2 = b ? ov2 : v1; ni2 = b ? oi2 : i1;
        }
        v1 = nv1; i1 = ni1; v2 = nv2; i2 = ni2;
    }
    if (sg == 0) {
        out[GSZ + 2*t]           = v1;
        out[GSZ + 2*t + 1]       = v2;
        out[GSZ + VSZ + 2*t]     = (float)i1;
        out[GSZ + VSZ + 2*t + 1] = (float)i2;
    }
}

extern "C" void kernel_launch(void* const* d_in, const int* in_sizes, int n_in,
                              void* d_out, int out_size, void* d_ws, size_t ws_size,
                              hipStream_t stream) {
    (void)in_sizes; (void)n_in; (void)ws_size; (void)out_size;
    const float* x = (const float*)d_in[0];
    const float* w = (const float*)d_in[1];
    float* out     = (float*)d_out;
    f16* WH = (f16*)d_ws;
    f16* WL = WH + WFRAG;

    split_w_kernel<<<128, 256, 0, stream>>>(w, WH, WL);
    router_kernel<<<TOKENS/BM, 512, 0, stream>>>(x, WH, WL, out);
}

// Round 6
// 370.902 us; speedup vs baseline: 1.1446x; 1.0018x over previous
//
#include <hip/hip_runtime.h>
#include <stdint.h>

typedef float f32x4 __attribute__((ext_vector_type(4)));
typedef _Float16 f16;
typedef _Float16 f16x8 __attribute__((ext_vector_type(8)));

#define TOKENS 16384
#define DIM    4096
#define NEXP   64
#define BM     32                  // tokens per block
#define GSZ    (TOKENS*NEXP)
#define VSZ    (TOKENS*2)
#define WFRAG  262144              // f16 elems per split array: 128 kk * 4 nt * 64 lanes * 8
#define STEPS  16                  // 32-k steps per wave (wave K-slice = 512)

// non-temporal 16B load: x lines are single-use; nt avoids displacing the
// harness's dirty poison lines from L2/L3 (no writeback storm).
__device__ __forceinline__ f32x4 ntload4(const float* p) {
    return __builtin_nontemporal_load((const f32x4*)p);
}

// fp32 -> fp16 hi/lo split (Markidis): v = h + l + O(2^-22 |v|)
__device__ __forceinline__ void split8(f32x4 a, f32x4 b, f16x8& h, f16x8& l) {
#pragma unroll
    for (int i = 0; i < 4; ++i) {
        float v = a[i]; f16 hi = (f16)v;
        h[i] = hi; l[i] = (f16)(v - (float)hi);
    }
#pragma unroll
    for (int i = 0; i < 4; ++i) {
        float v = b[i]; f16 hi = (f16)v;
        h[4+i] = hi; l[4+i] = (f16)(v - (float)hi);
    }
}

// Kernel A: split w into fp16 hi/lo in MFMA B-fragment order:
// slot s = (kk*4 + nt)*64 + lane -> expert e = nt*16 + (lane&15),
// k = kk*32 + (lane>>4)*8, 8 contiguous f16. 1 MB total.
__global__ void split_w_kernel(const float* __restrict__ w,
                               f16* __restrict__ WH, f16* __restrict__ WL) {
    const int s    = blockIdx.x * 256 + threadIdx.x;    // 0..32767
    const int lane = s & 63;
    const int nt   = (s >> 6) & 3;
    const int kk   = s >> 8;
    const int e    = nt*16 + (lane & 15);
    const int k8   = kk*32 + (lane >> 4)*8;
    const f32x4* wp = (const f32x4*)(w + (size_t)e*DIM + k8);
    f32x4 a = wp[0], b = wp[1];
    f16x8 h, l;
    split8(a, b, h, l);
    *(f16x8*)(WH + (size_t)s*8) = h;
    *(f16x8*)(WL + (size_t)s*8) = l;
}

// Kernel B: 512 threads = 8 K-split waves, BM=32 tokens x 64 experts/block.
// x loads NON-TEMPORAL (single-use stream), B fragments cacheable (L2-hot).
// No LDS / barriers in main loop. Epilogue: LDS reduce + softmax/top2.
__global__ __launch_bounds__(512, 4)
void router_kernel(const float* __restrict__ x,
                   const f16* __restrict__ WH, const f16* __restrict__ WL,
                   float* __restrict__ out)
{
    __shared__ float red[4][BM*NEXP];   // 32 KB

    const int tid  = threadIdx.x;
    const int lane = tid & 63;
    const int wv   = tid >> 6;          // 0..7
    const int tok0 = blockIdx.x * BM;
    const int l15  = lane & 15;
    const int lk   = lane >> 4;         // 0..3

    const float* ax = x + (size_t)(tok0 + l15)*DIM + wv*512 + lk*8;
    const f16x8* BH = (const f16x8*)WH;
    const f16x8* BL = (const f16x8*)WL;
    const int fb0 = (wv*16)*4*64 + lane;   // B frag index base for step 0

    f32x4 acc[2][4];
#pragma unroll
    for (int m = 0; m < 2; ++m)
#pragma unroll
        for (int n = 0; n < 4; ++n) acc[m][n] = (f32x4){0.f,0.f,0.f,0.f};

    // preload step 0 x (non-temporal)
    f32x4 c00 = ntload4(ax);
    f32x4 c01 = ntload4(ax + 4);
    f32x4 c10 = ntload4(ax + (size_t)16*DIM);
    f32x4 c11 = ntload4(ax + (size_t)16*DIM + 4);

    for (int s = 0; s < STEPS; ++s) {
        // 1) issue next-step x loads first (longest latency path)
        f32x4 n00, n01, n10, n11;
        if (s + 1 < STEPS) {
            const float* np = ax + (s+1)*32;
            n00 = ntload4(np);
            n01 = ntload4(np + 4);
            n10 = ntload4(np + (size_t)16*DIM);
            n11 = ntload4(np + (size_t)16*DIM + 4);
        }
        // 2) first B fragment pair for this step (cacheable: L2-hot reuse)
        const int ib = fb0 + s*4*64;
        f16x8 bh0 = BH[ib], bl0 = BL[ib];
        // 3) split current x in-register
        f16x8 ah0, al0, ah1, al1;
        split8(c00, c01, ah0, al0);
        split8(c10, c11, ah1, al1);
        // 4) n-loop with 1-deep B prefetch
#pragma unroll
        for (int n = 0; n < 4; ++n) {
            f16x8 bhn, bln;
            if (n < 3) { bhn = BH[ib + (n+1)*64]; bln = BL[ib + (n+1)*64]; }
            acc[0][n] = __builtin_amdgcn_mfma_f32_16x16x32_f16(ah0, bh0, acc[0][n], 0, 0, 0);
            acc[0][n] = __builtin_amdgcn_mfma_f32_16x16x32_f16(ah0, bl0, acc[0][n], 0, 0, 0);
            acc[0][n] = __builtin_amdgcn_mfma_f32_16x16x32_f16(al0, bh0, acc[0][n], 0, 0, 0);
            acc[1][n] = __builtin_amdgcn_mfma_f32_16x16x32_f16(ah1, bh0, acc[1][n], 0, 0, 0);
            acc[1][n] = __builtin_amdgcn_mfma_f32_16x16x32_f16(ah1, bl0, acc[1][n], 0, 0, 0);
            acc[1][n] = __builtin_amdgcn_mfma_f32_16x16x32_f16(al1, bh0, acc[1][n], 0, 0, 0);
            bh0 = bhn; bl0 = bln;
        }
        // 5) rotate x buffers
        c00 = n00; c01 = n01; c10 = n10; c11 = n11;
    }

    // ---- cross-wave reduction: two passes into red[0..3] ----
    // C/D fragment: col = lane&15 (expert within nt), row = lk*4 + i
    if (wv < 4) {
#pragma unroll
        for (int m = 0; m < 2; ++m)
#pragma unroll
            for (int n = 0; n < 4; ++n)
#pragma unroll
                for (int i = 0; i < 4; ++i)
                    red[wv][(m*16 + lk*4 + i)*NEXP + n*16 + l15] = acc[m][n][i];
    }
    __syncthreads();
    if (wv >= 4) {
#pragma unroll
        for (int m = 0; m < 2; ++m)
#pragma unroll
            for (int n = 0; n < 4; ++n)
#pragma unroll
                for (int i = 0; i < 4; ++i)
                    red[wv-4][(m*16 + lk*4 + i)*NEXP + n*16 + l15] += acc[m][n][i];
    }
    __syncthreads();

    // ---- softmax + top-2: 16 lanes per token, 4 experts per lane ----
    const int st = tid >> 4;       // token 0..31
    const int sg = tid & 15;       // expert quad 0..15
    const int ei = st*NEXP + sg*4;
    f32x4 s0 = *(const f32x4*)(&red[0][ei]);
    f32x4 s1 = *(const f32x4*)(&red[1][ei]);
    f32x4 s2 = *(const f32x4*)(&red[2][ei]);
    f32x4 s3 = *(const f32x4*)(&red[3][ei]);
    f32x4 lt = (s0 + s1) + (s2 + s3);
    float l[4] = {lt[0], lt[1], lt[2], lt[3]};

    float m = fmaxf(fmaxf(l[0], l[1]), fmaxf(l[2], l[3]));
#pragma unroll
    for (int off = 1; off < 16; off <<= 1) m = fmaxf(m, __shfl_xor(m, off));
    float g[4];
    float ssum = 0.f;
#pragma unroll
    for (int j = 0; j < 4; ++j) { g[j] = expf(l[j] - m); ssum += g[j]; }
#pragma unroll
    for (int off = 1; off < 16; off <<= 1) ssum += __shfl_xor(ssum, off);
    const float inv = 1.0f / ssum;
#pragma unroll
    for (int j = 0; j < 4; ++j) g[j] *= inv;

    const size_t t = (size_t)tok0 + st;
    f32x4 gv = {g[0], g[1], g[2], g[3]};
    *(f32x4*)(out + t*NEXP + sg*4) = gv;

    // top-2 on gate values (tie -> lower index, matching jax.lax.top_k)
    float v1 = g[0]; int i1 = sg*4;
    float v2 = -__builtin_inff(); int i2 = 1 << 30;
#pragma unroll
    for (int j = 1; j < 4; ++j) {
        float lv = g[j]; int li = sg*4 + j;
        bool b1 = (lv > v1) || (lv == v1 && li < i1);
        bool b2 = (lv > v2) || (lv == v2 && li < i2);
        float pv1 = v1; int pi1 = i1;
        v1 = b1 ? lv : v1;  i1 = b1 ? li : i1;
        v2 = b1 ? pv1 : (b2 ? lv : v2);
        i2 = b1 ? pi1 : (b2 ? li : i2);
    }
#pragma unroll
    for (int off = 1; off < 16; off <<= 1) {
        float ov1 = __shfl_xor(v1, off); int oi1 = __shfl_xor(i1, off);
        float ov2 = __shfl_xor(v2, off); int oi2 = __shfl_xor(i2, off);
        bool afirst = (v1 > ov1) || (v1 == ov1 && i1 < oi1);
        float nv1, nv2; int ni1, ni2;
        if (afirst) {
            nv1 = v1; ni1 = i1;
            bool b = (v2 > ov1) || (v2 == ov1 && i2 < oi1);
            nv2 = b ? v2 : ov1; ni2 = b ? i2 : oi1;
        } else {
            nv1 = ov1; ni1 = oi1;
            bool b = (ov2 > v1) || (ov2 == v1 && oi2 < i1);
            nv2 = b ? ov2 : v1; ni2 = b ? oi2 : i1;
        }
        v1 = nv1; i1 = ni1; v2 = nv2; i2 = ni2;
    }
    if (sg == 0) {
        out[GSZ + 2*t]           = v1;
        out[GSZ + 2*t + 1]       = v2;
        out[GSZ + VSZ + 2*t]     = (float)i1;
        out[GSZ + VSZ + 2*t + 1] = (float)i2;
    }
}

extern "C" void kernel_launch(void* const* d_in, const int* in_sizes, int n_in,
                              void* d_out, int out_size, void* d_ws, size_t ws_size,
                              hipStream_t stream) {
    (void)in_sizes; (void)n_in; (void)ws_size; (void)out_size;
    const float* x = (const float*)d_in[0];
    const float* w = (const float*)d_in[1];
    float* out     = (float*)d_out;
    f16* WH = (f16*)d_ws;
    f16* WL = WH + WFRAG;

    split_w_kernel<<<128, 256, 0, stream>>>(w, WH, WL);
    router_kernel<<<TOKENS/BM, 512, 0, stream>>>(x, WH, WL, out);
}

// Round 7
// 369.927 us; speedup vs baseline: 1.1477x; 1.0026x over previous
//
#include <hip/hip_runtime.h>
#include <stdint.h>

typedef float f32x4 __attribute__((ext_vector_type(4)));
typedef _Float16 f16;
typedef _Float16 f16x8 __attribute__((ext_vector_type(8)));

#define TOKENS 16384
#define DIM    4096
#define NEXP   64
#define BM     32                  // tokens per block
#define GSZ    (TOKENS*NEXP)
#define VSZ    (TOKENS*2)
#define WFRAG  262144              // f16 elems per split array: 128 kk * 4 nt * 64 lanes * 8
#define STEPS  16                  // 32-k steps per wave (wave K-slice = 512)

// non-temporal 16B load for the single-use x stream (kept from r6 baseline)
__device__ __forceinline__ f32x4 ntload4(const float* p) {
    return __builtin_nontemporal_load((const f32x4*)p);
}

// fp32 -> fp16 hi/lo split (Markidis): v = h + l + O(2^-22 |v|)
__device__ __forceinline__ void split8(f32x4 a, f32x4 b, f16x8& h, f16x8& l) {
#pragma unroll
    for (int i = 0; i < 4; ++i) {
        float v = a[i]; f16 hi = (f16)v;
        h[i] = hi; l[i] = (f16)(v - (float)hi);
    }
#pragma unroll
    for (int i = 0; i < 4; ++i) {
        float v = b[i]; f16 hi = (f16)v;
        h[4+i] = hi; l[4+i] = (f16)(v - (float)hi);
    }
}

// Kernel A: split w into fp16 hi/lo in MFMA B-fragment order:
// slot s = (kk*4 + nt)*64 + lane -> expert e = nt*16 + (lane&15),
// k = kk*32 + (lane>>4)*8, 8 contiguous f16. 1 MB total.
__global__ void split_w_kernel(const float* __restrict__ w,
                               f16* __restrict__ WH, f16* __restrict__ WL) {
    const int s    = blockIdx.x * 256 + threadIdx.x;    // 0..32767
    const int lane = s & 63;
    const int nt   = (s >> 6) & 3;
    const int kk   = s >> 8;
    const int e    = nt*16 + (lane & 15);
    const int k8   = kk*32 + (lane >> 4)*8;
    const f32x4* wp = (const f32x4*)(w + (size_t)e*DIM + k8);
    f32x4 a = wp[0], b = wp[1];
    f16x8 h, l;
    split8(a, b, h, l);
    *(f16x8*)(WH + (size_t)s*8) = h;
    *(f16x8*)(WL + (size_t)s*8) = l;
}

// Kernel B: 512 threads = 8 K-split waves. ISSUE-ORDER FIX: per step, all 8
// B(s) fragment loads are issued FIRST (oldest in the in-order vmcnt queue),
// then the 4 x(s+1) prefetch loads (youngest). MFMA waits on B therefore do
// NOT drain the x prefetch; x stays in flight across the MFMA phase and is
// only waited on one full step later (with 12 younger ops outstanding).
__global__ __launch_bounds__(512, 4)
void router_kernel(const float* __restrict__ x,
                   const f16* __restrict__ WH, const f16* __restrict__ WL,
                   float* __restrict__ out)
{
    __shared__ float red[4][BM*NEXP];   // 32 KB

    const int tid  = threadIdx.x;
    const int lane = tid & 63;
    const int wv   = tid >> 6;          // 0..7
    const int tok0 = blockIdx.x * BM;
    const int l15  = lane & 15;
    const int lk   = lane >> 4;         // 0..3

    const float* ax = x + (size_t)(tok0 + l15)*DIM + wv*512 + lk*8;
    const f16x8* BH = (const f16x8*)WH;
    const f16x8* BL = (const f16x8*)WL;
    const int fb0 = (wv*16)*4*64 + lane;   // B frag index base for step 0

    f32x4 acc[2][4];
#pragma unroll
    for (int m = 0; m < 2; ++m)
#pragma unroll
        for (int n = 0; n < 4; ++n) acc[m][n] = (f32x4){0.f,0.f,0.f,0.f};

    // preload step 0 x (non-temporal)
    f32x4 c00 = ntload4(ax);
    f32x4 c01 = ntload4(ax + 4);
    f32x4 c10 = ntload4(ax + (size_t)16*DIM);
    f32x4 c11 = ntload4(ax + (size_t)16*DIM + 4);

    for (int s = 0; s < STEPS; ++s) {
        // 1) B(s): all 8 fragment loads first — OLDEST in the vmcnt queue.
        const int ib = fb0 + s*4*64;
        f16x8 bh0 = BH[ib],       bl0 = BL[ib];
        f16x8 bh1 = BH[ib + 64],  bl1 = BL[ib + 64];
        f16x8 bh2 = BH[ib + 128], bl2 = BL[ib + 128];
        f16x8 bh3 = BH[ib + 192], bl3 = BL[ib + 192];
        // 2) x(s+1) prefetch — YOUNGEST; stays in flight through the MFMAs.
        f32x4 n00, n01, n10, n11;
        if (s + 1 < STEPS) {
            const float* np = ax + (s+1)*32;
            n00 = ntload4(np);
            n01 = ntload4(np + 4);
            n10 = ntload4(np + (size_t)16*DIM);
            n11 = ntload4(np + (size_t)16*DIM + 4);
        }
        // 3) split current x in-register (no memory wait)
        f16x8 ah0, al0, ah1, al1;
        split8(c00, c01, ah0, al0);
        split8(c10, c11, ah1, al1);
        // 4) MFMAs: waits drain only B(s) (oldest), never the x prefetch.
        acc[0][0] = __builtin_amdgcn_mfma_f32_16x16x32_f16(ah0, bh0, acc[0][0], 0, 0, 0);
        acc[0][0] = __builtin_amdgcn_mfma_f32_16x16x32_f16(ah0, bl0, acc[0][0], 0, 0, 0);
        acc[0][0] = __builtin_amdgcn_mfma_f32_16x16x32_f16(al0, bh0, acc[0][0], 0, 0, 0);
        acc[1][0] = __builtin_amdgcn_mfma_f32_16x16x32_f16(ah1, bh0, acc[1][0], 0, 0, 0);
        acc[1][0] = __builtin_amdgcn_mfma_f32_16x16x32_f16(ah1, bl0, acc[1][0], 0, 0, 0);
        acc[1][0] = __builtin_amdgcn_mfma_f32_16x16x32_f16(al1, bh0, acc[1][0], 0, 0, 0);
        acc[0][1] = __builtin_amdgcn_mfma_f32_16x16x32_f16(ah0, bh1, acc[0][1], 0, 0, 0);
        acc[0][1] = __builtin_amdgcn_mfma_f32_16x16x32_f16(ah0, bl1, acc[0][1], 0, 0, 0);
        acc[0][1] = __builtin_amdgcn_mfma_f32_16x16x32_f16(al0, bh1, acc[0][1], 0, 0, 0);
        acc[1][1] = __builtin_amdgcn_mfma_f32_16x16x32_f16(ah1, bh1, acc[1][1], 0, 0, 0);
        acc[1][1] = __builtin_amdgcn_mfma_f32_16x16x32_f16(ah1, bl1, acc[1][1], 0, 0, 0);
        acc[1][1] = __builtin_amdgcn_mfma_f32_16x16x32_f16(al1, bh1, acc[1][1], 0, 0, 0);
        acc[0][2] = __builtin_amdgcn_mfma_f32_16x16x32_f16(ah0, bh2, acc[0][2], 0, 0, 0);
        acc[0][2] = __builtin_amdgcn_mfma_f32_16x16x32_f16(ah0, bl2, acc[0][2], 0, 0, 0);
        acc[0][2] = __builtin_amdgcn_mfma_f32_16x16x32_f16(al0, bh2, acc[0][2], 0, 0, 0);
        acc[1][2] = __builtin_amdgcn_mfma_f32_16x16x32_f16(ah1, bh2, acc[1][2], 0, 0, 0);
        acc[1][2] = __builtin_amdgcn_mfma_f32_16x16x32_f16(ah1, bl2, acc[1][2], 0, 0, 0);
        acc[1][2] = __builtin_amdgcn_mfma_f32_16x16x32_f16(al1, bh2, acc[1][2], 0, 0, 0);
        acc[0][3] = __builtin_amdgcn_mfma_f32_16x16x32_f16(ah0, bh3, acc[0][3], 0, 0, 0);
        acc[0][3] = __builtin_amdgcn_mfma_f32_16x16x32_f16(ah0, bl3, acc[0][3], 0, 0, 0);
        acc[0][3] = __builtin_amdgcn_mfma_f32_16x16x32_f16(al0, bh3, acc[0][3], 0, 0, 0);
        acc[1][3] = __builtin_amdgcn_mfma_f32_16x16x32_f16(ah1, bh3, acc[1][3], 0, 0, 0);
        acc[1][3] = __builtin_amdgcn_mfma_f32_16x16x32_f16(ah1, bl3, acc[1][3], 0, 0, 0);
        acc[1][3] = __builtin_amdgcn_mfma_f32_16x16x32_f16(al1, bh3, acc[1][3], 0, 0, 0);
        // 5) rotate x buffers (register renaming; wait happens at next split)
        c00 = n00; c01 = n01; c10 = n10; c11 = n11;
    }

    // ---- cross-wave reduction: two passes into red[0..3] ----
    // C/D fragment: col = lane&15 (expert within nt), row = lk*4 + i
    if (wv < 4) {
#pragma unroll
        for (int m = 0; m < 2; ++m)
#pragma unroll
            for (int n = 0; n < 4; ++n)
#pragma unroll
                for (int i = 0; i < 4; ++i)
                    red[wv][(m*16 + lk*4 + i)*NEXP + n*16 + l15] = acc[m][n][i];
    }
    __syncthreads();
    if (wv >= 4) {
#pragma unroll
        for (int m = 0; m < 2; ++m)
#pragma unroll
            for (int n = 0; n < 4; ++n)
#pragma unroll
                for (int i = 0; i < 4; ++i)
                    red[wv-4][(m*16 + lk*4 + i)*NEXP + n*16 + l15] += acc[m][n][i];
    }
    __syncthreads();

    // ---- softmax + top-2: 16 lanes per token, 4 experts per lane ----
    const int st = tid >> 4;       // token 0..31
    const int sg = tid & 15;       // expert quad 0..15
    const int ei = st*NEXP + sg*4;
    f32x4 s0 = *(const f32x4*)(&red[0][ei]);
    f32x4 s1 = *(const f32x4*)(&red[1][ei]);
    f32x4 s2 = *(const f32x4*)(&red[2][ei]);
    f32x4 s3 = *(const f32x4*)(&red[3][ei]);
    f32x4 lt = (s0 + s1) + (s2 + s3);
    float l[4] = {lt[0], lt[1], lt[2], lt[3]};

    float m = fmaxf(fmaxf(l[0], l[1]), fmaxf(l[2], l[3]));
#pragma unroll
    for (int off = 1; off < 16; off <<= 1) m = fmaxf(m, __shfl_xor(m, off));
    float g[4];
    float ssum = 0.f;
#pragma unroll
    for (int j = 0; j < 4; ++j) { g[j] = expf(l[j] - m); ssum += g[j]; }
#pragma unroll
    for (int off = 1; off < 16; off <<= 1) ssum += __shfl_xor(ssum, off);
    const float inv = 1.0f / ssum;
#pragma unroll
    for (int j = 0; j < 4; ++j) g[j] *= inv;

    const size_t t = (size_t)tok0 + st;
    f32x4 gv = {g[0], g[1], g[2], g[3]};
    *(f32x4*)(out + t*NEXP + sg*4) = gv;

    // top-2 on gate values (tie -> lower index, matching jax.lax.top_k)
    float v1 = g[0]; int i1 = sg*4;
    float v2 = -__builtin_inff(); int i2 = 1 << 30;
#pragma unroll
    for (int j = 1; j < 4; ++j) {
        float lv = g[j]; int li = sg*4 + j;
        bool b1 = (lv > v1) || (lv == v1 && li < i1);
        bool b2 = (lv > v2) || (lv == v2 && li < i2);
        float pv1 = v1; int pi1 = i1;
        v1 = b1 ? lv : v1;  i1 = b1 ? li : i1;
        v2 = b1 ? pv1 : (b2 ? lv : v2);
        i2 = b1 ? pi1 : (b2 ? li : i2);
    }
#pragma unroll
    for (int off = 1; off < 16; off <<= 1) {
        float ov1 = __shfl_xor(v1, off); int oi1 = __shfl_xor(i1, off);
        float ov2 = __shfl_xor(v2, off); int oi2 = __shfl_xor(i2, off);
        bool afirst = (v1 > ov1) || (v1 == ov1 && i1 < oi1);
        float nv1, nv2; int ni1, ni2;
        if (afirst) {
            nv1 = v1; ni1 = i1;
            bool b = (v2 > ov1) || (v2 == ov1 && i2 < oi1);
            nv2 = b ? v2 : ov1; ni2 = b ? i2 : oi1;
        } else {
            nv1 = ov1; ni1 = oi1;
            bool b = (ov2 > v1) || (ov2 == v1 && oi2 < i1);
            nv2 = b ? ov2 : v1; ni2 = b ? oi2 : i1;
        }
        v1 = nv1; i1 = ni1; v2 = nv2; i2 = ni2;
    }
    if (sg == 0) {
        out[GSZ + 2*t]           = v1;
        out[GSZ + 2*t + 1]       = v2;
        out[GSZ + VSZ + 2*t]     = (float)i1;
        out[GSZ + VSZ + 2*t + 1] = (float)i2;
    }
}

extern "C" void kernel_launch(void* const* d_in, const int* in_sizes, int n_in,
                              void* d_out, int out_size, void* d_ws, size_t ws_size,
                              hipStream_t stream) {
    (void)in_sizes; (void)n_in; (void)ws_size; (void)out_size;
    const float* x = (const float*)d_in[0];
    const float* w = (const float*)d_in[1];
    float* out     = (float*)d_out;
    f16* WH = (f16*)d_ws;
    f16* WL = WH + WFRAG;

    split_w_kernel<<<128, 256, 0, stream>>>(w, WH, WL);
    router_kernel<<<TOKENS/BM, 512, 0, stream>>>(x, WH, WL, out);
}